// Round 5
// baseline (164.077 us; speedup 1.0000x reference)
//
#include <hip/hip_runtime.h>

// ---------------------------------------------------------------------------
// DistillationLoss, round 5.
// Structure change: NO LDS in pair passes. Packed B arrays (x,y,z,|b|^2) are
// pre-built in ws; each wave loads a 64-point chunk coalesced into per-lane
// VGPRs, then v_readlane extracts each point into SGPRs feeding scalar
// v_fma/v_min (1 SGPR operand per instr). A-side row constants unduplicated.
// VGPR <= 64 (__launch_bounds__(256,8)) -> 8 waves/SIMD; no barriers.
// partial min m = |b|^2 - 2 a.b (row |a|^2 added at sqrt stage, from packed w).
// 3 launches: init+pack -> mega (4 min passes + argmin + edge) -> post.
// ---------------------------------------------------------------------------

#define BLK 256
#define TA 8                      // rows per thread -> 2048 rows per block
#define JC 128                    // B points per y-chunk (2 chunks of 64)

__device__ __forceinline__ float wave_reduce_sum(float v) {
#pragma unroll
  for (int o = 32; o > 0; o >>= 1) v += __shfl_down(v, o, 64);
  return v;
}

// total-order float -> uint (monotone)
__device__ __forceinline__ unsigned flipf(float f) {
  unsigned b = __float_as_uint(f);
  return (b & 0x80000000u) ? ~b : (b | 0x80000000u);
}
__device__ __forceinline__ float unflipf(unsigned u) {
  unsigned b = (u & 0x80000000u) ? (u ^ 0x80000000u) : ~u;
  return __uint_as_float(b);
}

__device__ __forceinline__ float rdlanef(float v, int lane) {
  return __int_as_float(__builtin_amdgcn_readlane(__float_as_int(v), lane));
}

// Init + pack. Packed arrays: (x, y, z, |p|^2) per point, float4.
__global__ void init_ws_kernel(unsigned long long* __restrict__ min64, int n64,
                               unsigned* __restrict__ minbits, int nmin,
                               float* __restrict__ zr, int nz,
                               float4* __restrict__ svp, const float* __restrict__ sv,
                               float4* __restrict__ tpp, const float* __restrict__ tp,
                               float4* __restrict__ gpp, const float* __restrict__ gp,
                               float4* __restrict__ tvp, const float* __restrict__ tv,
                               int n) {
  const int stride = gridDim.x * blockDim.x;
  const int t0 = blockIdx.x * blockDim.x + threadIdx.x;
  for (int i = t0; i < n64; i += stride) min64[i] = ~0ull;
  for (int i = t0; i < nmin; i += stride) minbits[i] = 0xFF800000u;  // flip(+inf)
  for (int i = t0; i < nz; i += stride) zr[i] = 0.0f;                // also cnt=0
  for (int i = t0; i < n; i += stride) {
    float x, y, z;
    x = sv[3 * i]; y = sv[3 * i + 1]; z = sv[3 * i + 2];
    svp[i] = make_float4(x, y, z, fmaf(x, x, fmaf(y, y, z * z)));
    x = tp[3 * i]; y = tp[3 * i + 1]; z = tp[3 * i + 2];
    tpp[i] = make_float4(x, y, z, fmaf(x, x, fmaf(y, y, z * z)));
    x = gp[3 * i]; y = gp[3 * i + 1]; z = gp[3 * i + 2];
    gpp[i] = make_float4(x, y, z, fmaf(x, x, fmaf(y, y, z * z)));
    x = tv[3 * i]; y = tv[3 * i + 1]; z = tv[3 * i + 2];
    tvp[i] = make_float4(x, y, z, fmaf(x, x, fmaf(y, y, z * z)));
  }
}

struct Desc {
  const float4* A[5];    // packed row arrays
  const float4* B[5];    // packed col arrays
  void* out[5];          // unsigned* for 0-3, unsigned long long* for 4
  const int* fc; int f;
  const float* sv;
  float* nbr; float* deg; float* acc;
  int nRows, nCols;
};

// blockIdx.z: 0-3 chamfer min passes, 4 argmin pass, 5 edge pass.
__global__ void __launch_bounds__(BLK, 8) mega_kernel(Desc d) {
  const int pass = blockIdx.z;
  const int t = threadIdx.x;

  if (pass == 5) {
    // ---- edge + laplacian accumulation (grid-stride over 3F edges) ----
    const int nE = 3 * d.f;
    const int bid = blockIdx.y * gridDim.x + blockIdx.x;
    const int stride = gridDim.x * gridDim.y * BLK;
    float es = 0.f;
    for (int e = bid * BLK + t; e < nE; e += stride) {
      int a, b;
      if (e < d.f)          { a = d.fc[3 * e + 0];  b = d.fc[3 * e + 1]; }
      else if (e < 2 * d.f) { int q = e - d.f;     a = d.fc[3 * q + 1]; b = d.fc[3 * q + 2]; }
      else                  { int q = e - 2 * d.f; a = d.fc[3 * q + 2]; b = d.fc[3 * q + 0]; }
      float ax = d.sv[3 * a], ay = d.sv[3 * a + 1], az = d.sv[3 * a + 2];
      float bx = d.sv[3 * b], by = d.sv[3 * b + 1], bz = d.sv[3 * b + 2];
      float dx = ax - bx, dy = ay - by, dz = az - bz;
      es += fmaf(dx, dx, fmaf(dy, dy, dz * dz));
      atomicAdd(&d.nbr[3 * a + 0], bx);
      atomicAdd(&d.nbr[3 * a + 1], by);
      atomicAdd(&d.nbr[3 * a + 2], bz);
      atomicAdd(&d.nbr[3 * b + 0], ax);
      atomicAdd(&d.nbr[3 * b + 1], ay);
      atomicAdd(&d.nbr[3 * b + 2], az);
      atomicAdd(&d.deg[a], 1.0f);
      atomicAdd(&d.deg[b], 1.0f);
    }
    es = wave_reduce_sum(es);
    if ((t & 63) == 0) atomicAdd(&d.acc[4], es);
    return;
  }

  // ---- pair pass: rows in registers, B chunk in per-lane VGPRs ----
  const float4* __restrict__ A = d.A[pass];
  const float4* __restrict__ B = d.B[pass];
  const int lane = t & 63;
  const int j0 = blockIdx.y * JC;

  // two 64-point chunks, coalesced loads (issued before row loads)
  float4 bb[2];
  {
    int ja = j0 + lane;
    int jb = j0 + 64 + lane;
    bb[0] = (ja < d.nCols) ? B[ja] : make_float4(0.f, 0.f, 0.f, __int_as_float(0x7f800000));
    bb[1] = (jb < d.nCols) ? B[jb] : make_float4(0.f, 0.f, 0.f, __int_as_float(0x7f800000));
  }

  const int rowBase = blockIdx.x * (TA * BLK) + t;
  float nax[TA], nay[TA], naz[TA], m[TA];
#pragma unroll
  for (int k = 0; k < TA; ++k) {
    int r = rowBase + k * BLK;
    int rc = (r < d.nRows) ? r : 0;
    float4 a = A[rc];
    nax[k] = -2.0f * a.x;
    nay[k] = -2.0f * a.y;
    naz[k] = -2.0f * a.z;
    m[k] = __int_as_float(0x7f800000);
  }

  if (pass < 4) {
#pragma unroll
    for (int half = 0; half < 2; ++half) {
      float4 bp = bb[half];
#pragma unroll 8
      for (int c = 0; c < 64; ++c) {
        float bx = rdlanef(bp.x, c);
        float by = rdlanef(bp.y, c);
        float bz = rdlanef(bp.z, c);
        float bw = rdlanef(bp.w, c);
#pragma unroll
        for (int k = 0; k < TA; ++k) {
          float dd = fmaf(naz[k], bz, bw);
          dd = fmaf(nay[k], by, dd);
          dd = fmaf(nax[k], bx, dd);
          m[k] = fminf(m[k], dd);
        }
      }
    }
    unsigned* __restrict__ out = (unsigned*)d.out[pass];
#pragma unroll
    for (int k = 0; k < TA; ++k) {
      int r = rowBase + k * BLK;
      if (r < d.nRows) atomicMin(out + r, flipf(m[k]));
    }
  } else {
    // argmin pass: index tracked as float (j < 2^24 exact)
    float idxf[TA];
#pragma unroll
    for (int k = 0; k < TA; ++k) idxf[k] = 0.f;
#pragma unroll
    for (int half = 0; half < 2; ++half) {
      float4 bp = bb[half];
      const float jbf = (float)(j0 + 64 * half);
#pragma unroll 8
      for (int c = 0; c < 64; ++c) {
        float bx = rdlanef(bp.x, c);
        float by = rdlanef(bp.y, c);
        float bz = rdlanef(bp.z, c);
        float bw = rdlanef(bp.w, c);
        float jf = jbf + (float)c;
#pragma unroll
        for (int k = 0; k < TA; ++k) {
          float dd = fmaf(naz[k], bz, bw);
          dd = fmaf(nay[k], by, dd);
          dd = fmaf(nax[k], bx, dd);
          bool cm = dd < m[k];
          m[k] = cm ? dd : m[k];
          idxf[k] = cm ? jf : idxf[k];
        }
      }
    }
    unsigned long long* __restrict__ out = (unsigned long long*)d.out[4];
#pragma unroll
    for (int k = 0; k < TA; ++k) {
      int r = rowBase + k * BLK;
      unsigned long long packed =
          ((unsigned long long)flipf(m[k]) << 32) | (unsigned)(int)idxf[k];
      if (r < d.nRows) atomicMin(out + r, packed);
    }
  }
}

// Fused tail. blockIdx.y: 0 smooth->acc[5], 1 normal->acc[6], 2-5 sqrt-sums
// ->acc[0..3]. Last block (ticket) computes the final scalar.
__global__ void __launch_bounds__(BLK) post_kernel(
    const float* __restrict__ sv, const float* __restrict__ sn,
    const float* __restrict__ tn,
    const float4* __restrict__ svp, const float4* __restrict__ tpp,
    const float4* __restrict__ gpp,
    const float* __restrict__ nbr,
    const float* __restrict__ deg, const unsigned* __restrict__ minbase,
    const unsigned long long* __restrict__ min64,
    int n, int p, int g, int f, float* __restrict__ acc,
    int* __restrict__ cnt, float* __restrict__ out) {
  const int task = blockIdx.y;
  const int i = blockIdx.x * blockDim.x + threadIdx.x;
  float s = 0.f;
  int accIdx;
  if (task == 0) {
    accIdx = 5;
    if (i < n) {
      float dd = fmaxf(deg[i], 1.0f);
      float lx = nbr[3 * i + 0] / dd - sv[3 * i + 0];
      float ly = nbr[3 * i + 1] / dd - sv[3 * i + 1];
      float lz = nbr[3 * i + 2] / dd - sv[3 * i + 2];
      s = sqrtf(fmaf(lx, lx, fmaf(ly, ly, lz * lz)));
    }
  } else if (task == 1) {
    accIdx = 6;
    if (i < n) {
      int idx = (int)(min64[i] & 0xffffffffull);
      float sx = sn[3 * i], sy = sn[3 * i + 1], sz = sn[3 * i + 2];
      float tx = tn[3 * idx], ty = tn[3 * idx + 1], tz = tn[3 * idx + 2];
      float num = fmaf(sx, tx, fmaf(sy, ty, sz * tz));
      float ns = sqrtf(fmaf(sx, sx, fmaf(sy, sy, sz * sz)));
      float nt = sqrtf(fmaf(tx, tx, fmaf(ty, ty, tz * tz)));
      s = num / (fmaxf(ns, 1e-8f) * fmaxf(nt, 1e-8f));
    }
  } else {
    const int seg = task - 2;
    accIdx = seg;
    const float4* Aarr = (seg == 1) ? tpp : (seg == 3) ? gpp : svp;
    const int off = (seg == 0) ? 0 : (seg == 1) ? n : (seg == 2) ? (n + p) : (2 * n + p);
    const int cntN = (seg == 1) ? p : n;
    if (i < cntN) {
      float mval = unflipf(minbase[off + i]);
      float aa = Aarr[i].w;   // |a|^2 from packed array
      s = sqrtf(fmaxf(mval + aa, 0.0f));
    }
  }
  s = wave_reduce_sum(s);
  if ((threadIdx.x & 63) == 0) atomicAdd(&acc[accIdx], s);

  __syncthreads();
  __threadfence();
  __shared__ int last;
  if (threadIdx.x == 0)
    last = (atomicAdd(cnt, 1) == (int)(gridDim.x * gridDim.y) - 1);
  __syncthreads();
  if (last && threadIdx.x == 0) {
    float a[7];
#pragma unroll
    for (int q = 0; q < 7; ++q) a[q] = atomicAdd(&acc[q], 0.0f);
    float lt = 0.5f * (a[0] / (float)n + a[1] / (float)p);
    float lg = 0.5f * (a[2] / (float)n + a[3] / (float)g);
    float chamfer = 0.7f * lt + 0.3f * lg;
    float edge = a[4] / (float)(3 * f);
    float smooth = a[5] / (float)n;
    float normal = 1.0f - a[6] / (float)n;
    out[0] = chamfer + 2.0f * edge + smooth + 0.5f * normal;
  }
}

extern "C" void kernel_launch(void* const* d_in, const int* in_sizes, int n_in,
                              void* d_out, int out_size, void* d_ws, size_t ws_size,
                              hipStream_t stream) {
  const float* sv = (const float*)d_in[0];
  const float* sn = (const float*)d_in[1];
  const float* tv = (const float*)d_in[2];
  const float* tn = (const float*)d_in[3];
  const float* tp = (const float*)d_in[4];
  const float* gp = (const float*)d_in[5];
  const int*   fc = (const int*)d_in[6];
  const int n = in_sizes[0] / 3;
  const int m = in_sizes[2] / 3;
  const int p = in_sizes[4] / 3;
  const int g = in_sizes[5] / 3;
  const int f = in_sizes[6] / 3;

  // ws layout: packed float4 arrays first (16B aligned), then scratch.
  char* w = (char*)d_ws;
  float4* svp = (float4*)w; w += (size_t)n * 16;
  float4* tpp = (float4*)w; w += (size_t)p * 16;
  float4* gpp = (float4*)w; w += (size_t)g * 16;
  float4* tvp = (float4*)w; w += (size_t)m * 16;
  unsigned long long* min64 = (unsigned long long*)w; w += (size_t)n * 8;
  unsigned* minbase = (unsigned*)w; w += (size_t)(n + p + n + g) * 4;
  float* nbr = (float*)w; w += (size_t)n * 3 * 4;   // zero region starts here
  float* deg = (float*)w; w += (size_t)n * 4;
  float* acc = (float*)w; w += 8 * 4;
  int* cnt = (int*)w;

  unsigned* minA_tp = minbase;
  unsigned* minB_tp = minA_tp + n;
  unsigned* minA_gt = minB_tp + p;
  unsigned* minB_gt = minA_gt + n;

  const int nmin = n + p + n + g;
  const int nz = n * 3 + n + 8 + 1;   // nbr, deg, acc, cnt

  init_ws_kernel<<<256, BLK, 0, stream>>>(min64, n, minbase, nmin,
                                          nbr, nz,
                                          svp, sv, tpp, tp, gpp, gp, tvp, tv, n);

  Desc d;
  d.A[0] = svp; d.B[0] = tpp; d.out[0] = minA_tp;
  d.A[1] = tpp; d.B[1] = svp; d.out[1] = minB_tp;
  d.A[2] = svp; d.B[2] = gpp; d.out[2] = minA_gt;
  d.A[3] = gpp; d.B[3] = svp; d.out[3] = minB_gt;
  d.A[4] = svp; d.B[4] = tvp; d.out[4] = min64;
  d.fc = fc; d.f = f; d.sv = sv;
  d.nbr = nbr; d.deg = deg; d.acc = acc;
  d.nRows = n; d.nCols = n;  // all passes 8192x8192

  // Grid: 4 x 64 x 6 = 1536 blocks; VGPR<=64 -> up to 8 blocks/CU resident.
  dim3 pgrid((n + TA * BLK - 1) / (TA * BLK), (n + JC - 1) / JC, 6);
  mega_kernel<<<pgrid, BLK, 0, stream>>>(d);

  dim3 tgrid((n + BLK - 1) / BLK, 6);
  post_kernel<<<tgrid, BLK, 0, stream>>>(sv, sn, tn, svp, tpp, gpp, nbr, deg,
                                         minbase, min64, n, p, g, f,
                                         acc, cnt, (float*)d_out);
}

// Round 6
// 138.166 us; speedup vs baseline: 1.1875x; 1.1875x over previous
//
#include <hip/hip_runtime.h>

// ---------------------------------------------------------------------------
// DistillationLoss, round 6: MFMA pair passes.
// d^2(a,b) = |a|^2 + |b|^2 - 2 a.b computed by ONE v_mfma_f32_32x32x16_bf16
// per 32x32 tile via split-bf16 packing (K slots):
//   A: k0-2=-2hi(a) k3-5=-2lo(a) k6-8=-2hi(a) k9=hi(aa) k10=lo(aa) k11,12=1
//   B: k0-2= hi(b)  k3-5= hi(b)  k6-8= lo(b)  k9,10=1   k11=hi(bb) k12=lo(bb)
//   => C = aa + bb - 2[hh+lh+hl]  (error ~5e-5, threshold is 0.29)
// Fragments pre-packed in ws by init (A-form: sv,tp,gp; B-form: sv,tp,gp,tv).
// Min passes: TR=2 row-tiles/wave, rowacc min in C-layout regs, cross-lane
// reduce, atomicMin(flip bits). Argmin pass: TR=1, packed u64 atomicMin.
// C/D layout (verified): col=lane&31, row=(reg&3)+8*(reg>>2)+4*(lane>>5).
// 3 launches: init(pack) -> mega(5 pair passes + edge) -> post(fused tail).
// ---------------------------------------------------------------------------

typedef short sh8 __attribute__((ext_vector_type(8)));
typedef float f32x16 __attribute__((ext_vector_type(16)));

#define BLK 256
#define TR 2          // row-tiles per wave (min passes)
#define JTILES 64     // col-tiles per chunk = 2048 cols

__device__ __forceinline__ float wave_reduce_sum(float v) {
#pragma unroll
  for (int o = 32; o > 0; o >>= 1) v += __shfl_down(v, o, 64);
  return v;
}

// total-order float -> uint (monotone)
__device__ __forceinline__ unsigned flipf(float f) {
  unsigned b = __float_as_uint(f);
  return (b & 0x80000000u) ? ~b : (b | 0x80000000u);
}
__device__ __forceinline__ float unflipf(unsigned u) {
  unsigned b = (u & 0x80000000u) ? (u ^ 0x80000000u) : ~u;
  return __uint_as_float(b);
}

__device__ __forceinline__ unsigned short f2bf(float x) {  // RNE f32->bf16
  unsigned u = __float_as_uint(x);
  unsigned r = (u + 0x7FFFu + ((u >> 16) & 1u)) >> 16;
  return (unsigned short)r;
}
__device__ __forceinline__ float bf2f(unsigned short b) {
  return __uint_as_float(((unsigned)b) << 16);
}

// Pack one point i into A-form (optional) and B-form fragment arrays.
// Frag addressing: tile t=i>>5, lane=i&31 holds k0-7, lane+32 holds k8-15.
__device__ void pack_pt(int i, float x, float y, float z, sh8* Ap, sh8* Bp) {
  float aa = fmaf(x, x, fmaf(y, y, z * z));
  unsigned short hx = f2bf(x), hy = f2bf(y), hz = f2bf(z);
  float lx = x - bf2f(hx), ly = y - bf2f(hy), lz = z - bf2f(hz);
  unsigned short haa = f2bf(aa);
  float laa = aa - bf2f(haa);
  const short ONE = (short)0x3F80;
  const int base = (i >> 5) * 64 + (i & 31);
  if (Ap) {
    unsigned short nhx = f2bf(-2.f * bf2f(hx)), nhy = f2bf(-2.f * bf2f(hy)),
                   nhz = f2bf(-2.f * bf2f(hz));
    unsigned short nlx = f2bf(-2.f * lx), nly = f2bf(-2.f * ly),
                   nlz = f2bf(-2.f * lz);
    sh8 lo, hi;
    lo[0] = (short)nhx; lo[1] = (short)nhy; lo[2] = (short)nhz;
    lo[3] = (short)nlx; lo[4] = (short)nly; lo[5] = (short)nlz;
    lo[6] = (short)nhx; lo[7] = (short)nhy;
    hi[0] = (short)nhz; hi[1] = (short)haa; hi[2] = (short)f2bf(laa);
    hi[3] = ONE; hi[4] = ONE; hi[5] = 0; hi[6] = 0; hi[7] = 0;
    Ap[base] = lo; Ap[base + 32] = hi;
  }
  {
    unsigned short lxb = f2bf(lx), lyb = f2bf(ly), lzb = f2bf(lz);
    sh8 lo, hi;
    lo[0] = (short)hx; lo[1] = (short)hy; lo[2] = (short)hz;
    lo[3] = (short)hx; lo[4] = (short)hy; lo[5] = (short)hz;
    lo[6] = (short)lxb; lo[7] = (short)lyb;
    hi[0] = (short)lzb; hi[1] = ONE; hi[2] = ONE;
    hi[3] = (short)haa; hi[4] = (short)f2bf(laa);
    hi[5] = 0; hi[6] = 0; hi[7] = 0;
    Bp[base] = lo; Bp[base + 32] = hi;
  }
}

struct Packs {
  sh8 *Asv, *Atp, *Agp;
  sh8 *Bsv, *Btp, *Bgp, *Btv;
};

__global__ void init_ws_kernel(Packs pk,
                               const float* __restrict__ sv,
                               const float* __restrict__ tp,
                               const float* __restrict__ gp,
                               const float* __restrict__ tv,
                               unsigned long long* __restrict__ min64, int n64,
                               unsigned* __restrict__ minbits, int nmin,
                               float* __restrict__ zr, int nz, int n) {
  const int stride = gridDim.x * blockDim.x;
  const int t0 = blockIdx.x * blockDim.x + threadIdx.x;
  for (int i = t0; i < n64; i += stride) min64[i] = ~0ull;
  for (int i = t0; i < nmin; i += stride) minbits[i] = 0xFF800000u;  // flip(+inf)
  for (int i = t0; i < nz; i += stride) zr[i] = 0.0f;                // also cnt=0
  for (int i = t0; i < n; i += stride) {
    pack_pt(i, sv[3 * i], sv[3 * i + 1], sv[3 * i + 2], pk.Asv, pk.Bsv);
    pack_pt(i, tp[3 * i], tp[3 * i + 1], tp[3 * i + 2], pk.Atp, pk.Btp);
    pack_pt(i, gp[3 * i], gp[3 * i + 1], gp[3 * i + 2], pk.Agp, pk.Bgp);
    pack_pt(i, tv[3 * i], tv[3 * i + 1], tv[3 * i + 2], (sh8*)0, pk.Btv);
  }
}

struct Desc {
  const sh8* Ap[5];
  const sh8* Bp[5];
  void* out[5];          // unsigned* for 0-3, unsigned long long* for 4
  const int* fc; int f;
  const float* sv;
  float* nbr; float* deg; float* acc;
};

// blockIdx.z: 0-3 chamfer min passes, 4 argmin, 5 edge. Grid (64, 4, 6).
__global__ void __launch_bounds__(BLK) mega_kernel(Desc d) {
  const int pass = blockIdx.z;
  const int t = threadIdx.x;

  if (pass == 5) {
    // ---- edge + laplacian accumulation (grid-stride over 3F edges) ----
    const int nE = 3 * d.f;
    const int bid = blockIdx.y * gridDim.x + blockIdx.x;
    const int stride = gridDim.x * gridDim.y * BLK;
    float es = 0.f;
    for (int e = bid * BLK + t; e < nE; e += stride) {
      int a, b;
      if (e < d.f)          { a = d.fc[3 * e + 0];  b = d.fc[3 * e + 1]; }
      else if (e < 2 * d.f) { int q = e - d.f;     a = d.fc[3 * q + 1]; b = d.fc[3 * q + 2]; }
      else                  { int q = e - 2 * d.f; a = d.fc[3 * q + 2]; b = d.fc[3 * q + 0]; }
      float ax = d.sv[3 * a], ay = d.sv[3 * a + 1], az = d.sv[3 * a + 2];
      float bx = d.sv[3 * b], by = d.sv[3 * b + 1], bz = d.sv[3 * b + 2];
      float dx = ax - bx, dy = ay - by, dz = az - bz;
      es += fmaf(dx, dx, fmaf(dy, dy, dz * dz));
      atomicAdd(&d.nbr[3 * a + 0], bx);
      atomicAdd(&d.nbr[3 * a + 1], by);
      atomicAdd(&d.nbr[3 * a + 2], bz);
      atomicAdd(&d.nbr[3 * b + 0], ax);
      atomicAdd(&d.nbr[3 * b + 1], ay);
      atomicAdd(&d.nbr[3 * b + 2], az);
      atomicAdd(&d.deg[a], 1.0f);
      atomicAdd(&d.deg[b], 1.0f);
    }
    es = wave_reduce_sum(es);
    if ((t & 63) == 0) atomicAdd(&d.acc[4], es);
    return;
  }

  const int wave = t >> 6, lane = t & 63;
  const int jt0 = blockIdx.y * JTILES;
  const float INF = __int_as_float(0x7f800000);
  f32x16 zc;
#pragma unroll
  for (int q = 0; q < 16; ++q) zc[q] = 0.f;

  const sh8* __restrict__ Ap = d.Ap[pass];
  const sh8* __restrict__ Bp = d.Bp[pass];

  if (pass < 4) {
    if (blockIdx.x >= 32) return;            // 32 x-blocks cover 256 row-tiles
    const int rt0 = (blockIdx.x * 4 + wave) * TR;
    sh8 af0 = Ap[rt0 * 64 + lane];
    sh8 af1 = Ap[(rt0 + 1) * 64 + lane];
    f32x16 r0, r1;
#pragma unroll
    for (int q = 0; q < 16; ++q) { r0[q] = INF; r1[q] = INF; }
#pragma unroll 2
    for (int jt = 0; jt < JTILES; ++jt) {
      sh8 bf = Bp[(jt0 + jt) * 64 + lane];
      f32x16 c0 = __builtin_amdgcn_mfma_f32_32x32x16_bf16(af0, bf, zc, 0, 0, 0);
      f32x16 c1 = __builtin_amdgcn_mfma_f32_32x32x16_bf16(af1, bf, zc, 0, 0, 0);
      r0 = __builtin_elementwise_min(r0, c0);
      r1 = __builtin_elementwise_min(r1, c1);
    }
    unsigned* __restrict__ out = (unsigned*)d.out[pass];
#pragma unroll
    for (int a = 0; a < TR; ++a) {
#pragma unroll
      for (int q = 0; q < 16; ++q) {
        float v = (a == 0) ? r0[q] : r1[q];
        v = fminf(v, __shfl_xor(v, 1));
        v = fminf(v, __shfl_xor(v, 2));
        v = fminf(v, __shfl_xor(v, 4));
        v = fminf(v, __shfl_xor(v, 8));
        v = fminf(v, __shfl_xor(v, 16));
        if ((lane & 31) == 0) {
          int row = (rt0 + a) * 32 + (q & 3) + 8 * (q >> 2) + 4 * (lane >> 5);
          atomicMin(out + row, flipf(v));
        }
      }
    }
  } else {
    // argmin pass, TR=1, all 64 x-blocks (256 row-tiles)
    const int rt = blockIdx.x * 4 + wave;
    sh8 af = Ap[rt * 64 + lane];
    f32x16 m;
    float idx[16];
#pragma unroll
    for (int q = 0; q < 16; ++q) { m[q] = INF; idx[q] = 0.f; }
#pragma unroll 2
    for (int jt = 0; jt < JTILES; ++jt) {
      sh8 bf = Bp[(jt0 + jt) * 64 + lane];
      f32x16 c = __builtin_amdgcn_mfma_f32_32x32x16_bf16(af, bf, zc, 0, 0, 0);
      float colf = (float)((jt0 + jt) * 32 + (lane & 31));
#pragma unroll
      for (int q = 0; q < 16; ++q) {
        bool cm = c[q] < m[q];
        m[q] = cm ? c[q] : m[q];
        idx[q] = cm ? colf : idx[q];
      }
    }
    unsigned long long* __restrict__ out = (unsigned long long*)d.out[4];
#pragma unroll
    for (int q = 0; q < 16; ++q) {
      float v = m[q], ix = idx[q];
#pragma unroll
      for (int s = 0; s < 5; ++s) {
        int msk = 1 << s;
        float ov = __shfl_xor(v, msk);
        float oi = __shfl_xor(ix, msk);
        bool take = (ov < v) || (ov == v && oi < ix);
        v = take ? ov : v;
        ix = take ? oi : ix;
      }
      if ((lane & 31) == 0) {
        int row = rt * 32 + (q & 3) + 8 * (q >> 2) + 4 * (lane >> 5);
        unsigned long long packed =
            ((unsigned long long)flipf(v) << 32) | (unsigned)(int)ix;
        atomicMin(out + row, packed);
      }
    }
  }
}

// Fused tail. blockIdx.y: 0 smooth->acc[5], 1 normal->acc[6], 2-5 sqrt-sums
// ->acc[0..3]. Last block (ticket) computes the final scalar.
__global__ void __launch_bounds__(BLK) post_kernel(
    const float* __restrict__ sv, const float* __restrict__ sn,
    const float* __restrict__ tn,
    const float* __restrict__ nbr, const float* __restrict__ deg,
    const unsigned* __restrict__ minbase,
    const unsigned long long* __restrict__ min64,
    int n, int p, int g, int f, float* __restrict__ acc,
    int* __restrict__ cnt, float* __restrict__ out) {
  const int task = blockIdx.y;
  const int i = blockIdx.x * blockDim.x + threadIdx.x;
  float s = 0.f;
  int accIdx;
  if (task == 0) {
    accIdx = 5;
    if (i < n) {
      float dd = fmaxf(deg[i], 1.0f);
      float lx = nbr[3 * i + 0] / dd - sv[3 * i + 0];
      float ly = nbr[3 * i + 1] / dd - sv[3 * i + 1];
      float lz = nbr[3 * i + 2] / dd - sv[3 * i + 2];
      s = sqrtf(fmaf(lx, lx, fmaf(ly, ly, lz * lz)));
    }
  } else if (task == 1) {
    accIdx = 6;
    if (i < n) {
      int idx = (int)(min64[i] & 0xffffffffull);
      float sx = sn[3 * i], sy = sn[3 * i + 1], sz = sn[3 * i + 2];
      float tx = tn[3 * idx], ty = tn[3 * idx + 1], tz = tn[3 * idx + 2];
      float num = fmaf(sx, tx, fmaf(sy, ty, sz * tz));
      float ns = sqrtf(fmaf(sx, sx, fmaf(sy, sy, sz * sz)));
      float nt = sqrtf(fmaf(tx, tx, fmaf(ty, ty, tz * tz)));
      s = num / (fmaxf(ns, 1e-8f) * fmaxf(nt, 1e-8f));
    }
  } else {
    const int seg = task - 2;
    accIdx = seg;
    const int off = (seg == 0) ? 0 : (seg == 1) ? n : (seg == 2) ? (n + p) : (2 * n + p);
    const int cntN = (seg == 1) ? p : n;
    if (i < cntN) {
      float d2 = unflipf(minbase[off + i]);   // full d^2 from MFMA
      s = sqrtf(fmaxf(d2, 0.0f));
    }
  }
  s = wave_reduce_sum(s);
  if ((threadIdx.x & 63) == 0) atomicAdd(&acc[accIdx], s);

  __syncthreads();
  __threadfence();
  __shared__ int last;
  if (threadIdx.x == 0)
    last = (atomicAdd(cnt, 1) == (int)(gridDim.x * gridDim.y) - 1);
  __syncthreads();
  if (last && threadIdx.x == 0) {
    float a[7];
#pragma unroll
    for (int q = 0; q < 7; ++q) a[q] = atomicAdd(&acc[q], 0.0f);
    float lt = 0.5f * (a[0] / (float)n + a[1] / (float)p);
    float lg = 0.5f * (a[2] / (float)n + a[3] / (float)g);
    float chamfer = 0.7f * lt + 0.3f * lg;
    float edge = a[4] / (float)(3 * f);
    float smooth = a[5] / (float)n;
    float normal = 1.0f - a[6] / (float)n;
    out[0] = chamfer + 2.0f * edge + smooth + 0.5f * normal;
  }
}

extern "C" void kernel_launch(void* const* d_in, const int* in_sizes, int n_in,
                              void* d_out, int out_size, void* d_ws, size_t ws_size,
                              hipStream_t stream) {
  const float* sv = (const float*)d_in[0];
  const float* sn = (const float*)d_in[1];
  const float* tv = (const float*)d_in[2];
  const float* tn = (const float*)d_in[3];
  const float* tp = (const float*)d_in[4];
  const float* gp = (const float*)d_in[5];
  const int*   fc = (const int*)d_in[6];
  const int n = in_sizes[0] / 3;
  const int m = in_sizes[2] / 3;
  const int p = in_sizes[4] / 3;
  const int g = in_sizes[5] / 3;
  const int f = in_sizes[6] / 3;

  // ws layout: fragment packs (32 B per point each form), then scratch.
  char* w = (char*)d_ws;
  Packs pk;
  pk.Asv = (sh8*)w; w += (size_t)n * 32;
  pk.Atp = (sh8*)w; w += (size_t)p * 32;
  pk.Agp = (sh8*)w; w += (size_t)g * 32;
  pk.Bsv = (sh8*)w; w += (size_t)n * 32;
  pk.Btp = (sh8*)w; w += (size_t)p * 32;
  pk.Bgp = (sh8*)w; w += (size_t)g * 32;
  pk.Btv = (sh8*)w; w += (size_t)m * 32;
  unsigned long long* min64 = (unsigned long long*)w; w += (size_t)n * 8;
  unsigned* minbase = (unsigned*)w; w += (size_t)(n + p + n + g) * 4;
  float* nbr = (float*)w; w += (size_t)n * 3 * 4;   // zero region starts here
  float* deg = (float*)w; w += (size_t)n * 4;
  float* acc = (float*)w; w += 8 * 4;
  int* cnt = (int*)w;

  unsigned* minA_tp = minbase;
  unsigned* minB_tp = minA_tp + n;
  unsigned* minA_gt = minB_tp + p;
  unsigned* minB_gt = minA_gt + n;

  const int nmin = n + p + n + g;
  const int nz = n * 3 + n + 8 + 1;   // nbr, deg, acc, cnt

  init_ws_kernel<<<64, BLK, 0, stream>>>(pk, sv, tp, gp, tv,
                                         min64, n, minbase, nmin, nbr, nz, n);

  Desc d;
  d.Ap[0] = pk.Asv; d.Bp[0] = pk.Btp; d.out[0] = minA_tp;
  d.Ap[1] = pk.Atp; d.Bp[1] = pk.Bsv; d.out[1] = minB_tp;
  d.Ap[2] = pk.Asv; d.Bp[2] = pk.Bgp; d.out[2] = minA_gt;
  d.Ap[3] = pk.Agp; d.Bp[3] = pk.Bsv; d.out[3] = minB_gt;
  d.Ap[4] = pk.Asv; d.Bp[4] = pk.Btv; d.out[4] = min64;
  d.fc = fc; d.f = f; d.sv = sv;
  d.nbr = nbr; d.deg = deg; d.acc = acc;

  // Grid: x=64 row-blocks (min passes use 32), y=4 col-chunks, z=6 passes.
  dim3 pgrid(64, 4, 6);
  mega_kernel<<<pgrid, BLK, 0, stream>>>(d);

  dim3 tgrid((n + BLK - 1) / BLK, 6);
  post_kernel<<<tgrid, BLK, 0, stream>>>(sv, sn, tn, nbr, deg,
                                         minbase, min64, n, p, g, f,
                                         acc, cnt, (float*)d_out);
}